// Round 1
// baseline (126.346 us; speedup 1.0000x reference)
//
#include <hip/hip_runtime.h>
#include <math.h>

#define QN 128
#define SN 512
#define DN 768
#define TDN 1536
#define CN 64

// ws layout (floats):
//   hqp: 2 * QN*TDN   (split-K partials for hq)
//   hsp: 2 * SN*TDN   (split-K partials for hs)
//   spart: 16 * QN*SN (split-J partial scores)
//   lossp: QN
#define HQP_ELEMS (2 * QN * TDN)
#define HSP_ELEMS (2 * SN * TDN)
#define SPART_ELEMS (16 * QN * SN)

// ---------------------------------------------------------------------------
// GEMM: C[m][n] = sum_k A[m][k] * W1[n][Koff + k]   (split-K into 2 halves)
// grid (24, 10, 2): x = n-tile(64), y<2 -> hq row-tiles, y>=2 -> hs row-tiles,
// z = K half. block 256 (16x16), micro 4x4, LDS stored transposed [kk][m].
// ---------------------------------------------------------------------------
__global__ __launch_bounds__(256) void gemm_split_kernel(
    const float* __restrict__ query, const float* __restrict__ support,
    const float* __restrict__ W1, float* __restrict__ hqp, float* __restrict__ hsp)
{
    const int nt = blockIdx.x;   // 0..23
    const int mt = blockIdx.y;   // 0..9
    const int kz = blockIdx.z;   // 0..1

    const float* A;
    float* Cout;
    int M0, Koff;
    if (mt < 2) { A = query;   M0 = mt * 64;       Koff = 0;  Cout = hqp + (size_t)kz * QN * TDN; }
    else        { A = support; M0 = (mt - 2) * 64; Koff = DN; Cout = hsp + (size_t)kz * SN * TDN; }

    const int tid  = threadIdx.x;
    const int tx   = tid & 15;
    const int ty   = tid >> 4;
    const int lrow = tid >> 2;   // 0..63
    const int lq   = tid & 3;    // 0..3

    __shared__ float As[16][68];
    __shared__ float Bs[16][68];

    float acc[4][4];
    #pragma unroll
    for (int i = 0; i < 4; ++i)
        #pragma unroll
        for (int j = 0; j < 4; ++j) acc[i][j] = 0.0f;

    const int k0base = kz * 384;
    for (int k0 = k0base; k0 < k0base + 384; k0 += 16) {
        float4 av = *(const float4*)&A [(size_t)(M0 + lrow) * DN  + k0 + lq * 4];
        float4 bv = *(const float4*)&W1[(size_t)(nt * 64 + lrow) * TDN + Koff + k0 + lq * 4];
        __syncthreads();
        As[lq*4+0][lrow] = av.x; As[lq*4+1][lrow] = av.y;
        As[lq*4+2][lrow] = av.z; As[lq*4+3][lrow] = av.w;
        Bs[lq*4+0][lrow] = bv.x; Bs[lq*4+1][lrow] = bv.y;
        Bs[lq*4+2][lrow] = bv.z; Bs[lq*4+3][lrow] = bv.w;
        __syncthreads();
        #pragma unroll
        for (int kk = 0; kk < 16; ++kk) {
            float4 a4 = *(const float4*)&As[kk][ty * 4];
            float4 b4 = *(const float4*)&Bs[kk][tx * 4];
            float a[4] = {a4.x, a4.y, a4.z, a4.w};
            float b[4] = {b4.x, b4.y, b4.z, b4.w};
            #pragma unroll
            for (int i = 0; i < 4; ++i)
                #pragma unroll
                for (int j = 0; j < 4; ++j)
                    acc[i][j] += a[i] * b[j];
        }
    }

    #pragma unroll
    for (int i = 0; i < 4; ++i) {
        float4 v = make_float4(acc[i][0], acc[i][1], acc[i][2], acc[i][3]);
        *(float4*)&Cout[(size_t)(M0 + ty * 4 + i) * TDN + nt * 64 + tx * 4] = v;
    }
}

// ---------------------------------------------------------------------------
// Score pass: spart[jc][q][s] = sum_{j in chunk jc} w2[j]*relu(hq[q][j]+hs[s][j]+b1[j])
// grid (16, 2, 8): jc, q-tile(64), s-tile(64). block 256 (16x16), micro 4x4.
// hq/hs staged transposed [jj][row] so compute reads are b128; split-K partials
// summed (and b1 added) at staging time.
// ---------------------------------------------------------------------------
__global__ __launch_bounds__(256) void score_kernel(
    const float* __restrict__ hqp, const float* __restrict__ hsp,
    const float* __restrict__ b1, const float* __restrict__ W2,
    float* __restrict__ spart)
{
    const int jc = blockIdx.x;   // 0..15
    const int qt = blockIdx.y;   // 0..1
    const int st = blockIdx.z;   // 0..7

    __shared__ float hqT[96][64];
    __shared__ float hsT[96][64];
    __shared__ float w2s[96];

    const int tid = threadIdx.x;

    #pragma unroll
    for (int l = 0; l < 6; ++l) {
        int idx  = tid + l * 256;         // 0..1535
        int row  = idx / 24;              // 0..63
        int quad = idx - row * 24;        // 0..23
        int j    = jc * 96 + quad * 4;
        float4 h0 = *(const float4*)&hqp[(size_t)(qt * 64 + row) * TDN + j];
        float4 h1 = *(const float4*)&hqp[(size_t)QN * TDN + (size_t)(qt * 64 + row) * TDN + j];
        float4 bb = *(const float4*)&b1[j];
        hqT[quad*4+0][row] = h0.x + h1.x + bb.x;
        hqT[quad*4+1][row] = h0.y + h1.y + bb.y;
        hqT[quad*4+2][row] = h0.z + h1.z + bb.z;
        hqT[quad*4+3][row] = h0.w + h1.w + bb.w;
        float4 g0 = *(const float4*)&hsp[(size_t)(st * 64 + row) * TDN + j];
        float4 g1 = *(const float4*)&hsp[(size_t)SN * TDN + (size_t)(st * 64 + row) * TDN + j];
        hsT[quad*4+0][row] = g0.x + g1.x;
        hsT[quad*4+1][row] = g0.y + g1.y;
        hsT[quad*4+2][row] = g0.z + g1.z;
        hsT[quad*4+3][row] = g0.w + g1.w;
    }
    if (tid < 24) {
        float4 w = *(const float4*)&W2[jc * 96 + tid * 4];
        w2s[tid*4+0] = w.x; w2s[tid*4+1] = w.y;
        w2s[tid*4+2] = w.z; w2s[tid*4+3] = w.w;
    }
    __syncthreads();

    const int tx = tid & 15;
    const int ty = tid >> 4;
    float acc[4][4];
    #pragma unroll
    for (int i = 0; i < 4; ++i)
        #pragma unroll
        for (int j = 0; j < 4; ++j) acc[i][j] = 0.0f;

    #pragma unroll 4
    for (int jj = 0; jj < 96; ++jj) {
        float4 a4 = *(const float4*)&hqT[jj][ty * 4];
        float4 b4 = *(const float4*)&hsT[jj][tx * 4];
        float w = w2s[jj];
        float a[4] = {a4.x, a4.y, a4.z, a4.w};
        float b[4] = {b4.x, b4.y, b4.z, b4.w};
        #pragma unroll
        for (int i = 0; i < 4; ++i)
            #pragma unroll
            for (int j = 0; j < 4; ++j)
                acc[i][j] += w * fmaxf(a[i] + b[j], 0.0f);
    }

    float* outp = spart + (size_t)jc * QN * SN;
    #pragma unroll
    for (int i = 0; i < 4; ++i) {
        float4 v = make_float4(acc[i][0], acc[i][1], acc[i][2], acc[i][3]);
        *(float4*)&outp[(size_t)(qt * 64 + ty * 4 + i) * SN + st * 64 + tx * 4] = v;
    }
}

// ---------------------------------------------------------------------------
// Per-query aggregation: label-segmented mean over S, log_softmax over C=64,
// argmax (lower index wins on ties), per-query loss partial + correct flag.
// grid 128, block 256.
// ---------------------------------------------------------------------------
__global__ __launch_bounds__(256) void agg_kernel(
    const float* __restrict__ spart, const int* __restrict__ labels,
    const int* __restrict__ tgt, float* __restrict__ lossp, float* __restrict__ out)
{
    const int q = blockIdx.x;
    __shared__ float cls_sum[CN];
    __shared__ float cls_cnt[CN];
    __shared__ float aggs[CN];

    const int tid = threadIdx.x;
    if (tid < CN) { cls_sum[tid] = 0.0f; cls_cnt[tid] = 0.0f; }
    __syncthreads();

    #pragma unroll
    for (int r = 0; r < 2; ++r) {
        int s = tid + r * 256;
        float sc = 0.0f;
        #pragma unroll
        for (int jcc = 0; jcc < 16; ++jcc)
            sc += spart[(size_t)jcc * QN * SN + (size_t)q * SN + s];
        int lab = labels[s];
        atomicAdd(&cls_sum[lab], sc);
        atomicAdd(&cls_cnt[lab], 1.0f);
    }
    __syncthreads();

    if (tid < CN) aggs[tid] = cls_sum[tid] / fmaxf(cls_cnt[tid], 1.0f);
    __syncthreads();

    if (tid < CN) {
        float v = aggs[tid];
        // max over 64 lanes
        float m = v;
        #pragma unroll
        for (int off = 1; off < 64; off <<= 1)
            m = fmaxf(m, __shfl_xor(m, off));
        // argmax, lower index wins ties
        float av = v; int am = tid;
        #pragma unroll
        for (int off = 1; off < 64; off <<= 1) {
            float ov = __shfl_xor(av, off);
            int   oi = __shfl_xor(am, off);
            if (ov > av || (ov == av && oi < am)) { av = ov; am = oi; }
        }
        // sum of exp(v - m)
        float e = expf(v - m);
        #pragma unroll
        for (int off = 1; off < 64; off <<= 1)
            e += __shfl_xor(e, off);
        if (tid == 0) {
            int t = tgt[q];
            float logp = aggs[t] - m - logf(e);
            lossp[q] = -logp / (float)QN;
            out[1 + q] = (am == t) ? 1.0f : 0.0f;
        }
    }
}

// ---------------------------------------------------------------------------
// Final loss reduction: 1 block, 128 threads.
// ---------------------------------------------------------------------------
__global__ __launch_bounds__(128) void loss_kernel(
    const float* __restrict__ lossp, float* __restrict__ out)
{
    const int tid = threadIdx.x;
    float v = lossp[tid];
    #pragma unroll
    for (int off = 1; off < 64; off <<= 1)
        v += __shfl_xor(v, off);
    __shared__ float partial[2];
    if ((tid & 63) == 0) partial[tid >> 6] = v;
    __syncthreads();
    if (tid == 0) out[0] = partial[0] + partial[1];
}

extern "C" void kernel_launch(void* const* d_in, const int* in_sizes, int n_in,
                              void* d_out, int out_size, void* d_ws, size_t ws_size,
                              hipStream_t stream) {
    const float* query   = (const float*)d_in[0];
    const float* support = (const float*)d_in[1];
    const float* W1      = (const float*)d_in[2];
    const float* b1      = (const float*)d_in[3];
    const float* W2      = (const float*)d_in[4];
    // d_in[5] = b2: cancels exactly under log_softmax/argmax (uniform shift) -> unused
    const int* labels = (const int*)d_in[6];
    const int* tgt    = (const int*)d_in[7];
    // d_in[8] = num_classes (compile-time 64)

    float* ws    = (float*)d_ws;
    float* hqp   = ws;                       // 2*QN*TDN
    float* hsp   = hqp + HQP_ELEMS;          // 2*SN*TDN
    float* spart = hsp + HSP_ELEMS;          // 16*QN*SN
    float* lossp = spart + SPART_ELEMS;      // QN
    float* out   = (float*)d_out;

    hipLaunchKernelGGL(gemm_split_kernel, dim3(24, 10, 2), dim3(256), 0, stream,
                       query, support, W1, hqp, hsp);
    hipLaunchKernelGGL(score_kernel, dim3(16, 2, 8), dim3(256), 0, stream,
                       hqp, hsp, b1, W2, spart);
    hipLaunchKernelGGL(agg_kernel, dim3(128), dim3(256), 0, stream,
                       spart, labels, tgt, lossp, out);
    hipLaunchKernelGGL(loss_kernel, dim3(1), dim3(128), 0, stream,
                       lossp, out);
}